// Round 9
// baseline (146.867 us; speedup 1.0000x reference)
//
#include <hip/hip_runtime.h>
#include <math.h>

#define B 32
#define P1 778
#define NF 1538
#define P2 3000
#define PARAM_DIM 61
#define LATENT 64

// ---- MFMA kd2 geometry ----
#define P1PAD 784            // 49 hand tiles of 16
#define NTH 49               // hand tiles
#define CHO 192              // obj pts per block (16 chunks cover 3000..3072)
#define NTO 12               // obj tiles (of 16) per block; all waves sweep all 12
#define NTOH 6               // MFMA cluster depth (dd[] register budget)
#define NCH 16               // obj chunks
#define NPART NCH            // h2o partial sets per (set,b)

#define RED1_BLKS 16
#define HC_BLKS 128
#define OC_BLKS 192
#define QF 385               // faces per quarter-split (3*385 + 383 = 1538)

// ---- merged dispatch 1: kd2-sweep blocks FIRST, then normals, then red1 ----
#define M_D2  (NCH * 64)               // 1024
#define M_NRM 256                      // 4 quarters * 2 sets * 32 batches
#define M_TOT (M_D2 + M_NRM + RED1_BLKS)
#define D3_TOT (OC_BLKS + HC_BLKS)

// ws layout (float offsets)
#define NP_OFF  0
#define NP_SZ   (4*2*B*P1*4)           // [quarter*2+set][b][p] float4 raw normals
#define OS_OFF  (NP_OFF + NP_SZ)       // 2*B*P2 o2h winning KEYS (uint)
#define OS_SZ   (2*B*P2)
#define HP_OFF  (OS_OFF + OS_SZ)
#define HP_SZ   (NPART*2*B*P1PAD)
#define R1_OFF  (HP_OFF + HP_SZ)
#define RH_OFF  (R1_OFF + RED1_BLKS*3)
#define RO_OFF  (RH_OFF + HC_BLKS)
#define CNT_OFF (RO_OFF + OC_BLKS)     // kd3 completion counter (zeroed in kd12)

typedef __attribute__((ext_vector_type(8))) short bf16x8;
typedef __attribute__((ext_vector_type(4))) float f32x4;
union U4 { uint4 u; bf16x8 v; };

static __device__ __forceinline__ unsigned umin2(unsigned a, unsigned b) { return a < b ? a : b; }
// top 16 bits of an f32 = bf16 by truncation (residual stays exactly representable)
static __device__ __forceinline__ unsigned bhi(float x) { return __float_as_uint(x) >> 16; }
static __device__ __forceinline__ float bres(float x, unsigned h) { return x - __uint_as_float(h << 16); }

// DPP min-reduce stage across a 16-lane row (no DS pipe, no waitcnt).
template <int CTRL>
static __device__ __forceinline__ float dpp_min(float x) {
  const int xi = __float_as_int(x);
  const int yi = __builtin_amdgcn_update_dpp(xi, xi, CTRL, 0xF, 0xF, false);
  return fminf(x, __int_as_float(yi));
}
static __device__ __forceinline__ float row_min16(float x) {
  x = dpp_min<0xB1>(x);    // quad_perm[1,0,3,2]
  x = dpp_min<0x4E>(x);    // quad_perm[2,3,0,1]
  x = dpp_min<0x124>(x);   // row_ror:4
  x = dpp_min<0x128>(x);   // row_ror:8
  return x;
}

// shared-memory union: kd1-branch (31.1 KB) vs kd2-branch (18.7 KB)
union SMem {
  struct { float4 sv[P1]; float sn[2][2336]; } d1;                     // 31136 B
  struct { float4 sVerts[P1PAD]; float4 sObj[CHO]; unsigned sKeys[4][CHO]; } d2; // 18688 B
};

// ---------------- D1: merged kd2-sweep ∥ normals ∥ red1 ----------------------
// bid <  M_D2           : MFMA distance sweep (writes OS keys + HP partials)
// bid <  M_D2+M_NRM     : vertex-normal quarter partials (face-split, R7 form)
// else                  : red1 input reductions (+ CNT zero)
// No intra-dispatch dependencies: sweep no longer reads NP (sign moved to kd3).
__global__ __launch_bounds__(256, 4) void kd12(
    const float* __restrict__ recon_x, const float* __restrict__ x,
    const float* __restrict__ mu, const float* __restrict__ logvar,
    const float* __restrict__ recon_xyz, const float* __restrict__ hand_xyz,
    const int* __restrict__ faces, const float* __restrict__ obj,
    float* __restrict__ ws) {
  __shared__ SMem sm;
  const int tid = threadIdx.x;
  const int bid = blockIdx.x;

  if (bid < M_D2) {
    // ================= kd2 sweep: (chunk, set, b) =================
    const int chunk = bid >> 6, rr = bid & 63, set = rr >> 5, b = rr & 31;
    const float* verts = (set == 0 ? recon_xyz : hand_xyz) + b * P1 * 3;
    const float* op = obj + (size_t)b * P2 * 3;

    for (int i = tid; i < P1PAD; i += 256) {
      float vx, vy, vz;
      if (i < P1) { vx = verts[3*i]; vy = verts[3*i+1]; vz = verts[3*i+2]; }
      else        { vx = vy = vz = 1.0e6f; }     // far pad row: never argmin
      sm.d2.sVerts[i] = make_float4(vx, vy, vz, vx*vx + vy*vy + vz*vz);
    }
    for (int i = tid; i < CHO; i += 256) {
      const int q = chunk * CHO + i;
      float ox, oy, oz;
      if (q < P2) { ox = op[3*q]; oy = op[3*q+1]; oz = op[3*q+2]; }
      else        { ox = oy = oz = 1.0e6f; }
      sm.d2.sObj[i] = make_float4(ox, oy, oz, ox*ox + oy*oy + oz*oz);
    }
    __syncthreads();

    // ---- pack B fragments (obj side) into registers, identical per wave ----
    const int l = tid & 63, wv = tid >> 6, g = l >> 4, cl = l & 15;
    U4 bw[NTO];
    #pragma unroll
    for (int j = 0; j < NTO; ++j) {
      const float4 o = sm.d2.sObj[j * 16 + cl];
      unsigned u0 = 0u, u1 = 0u, u2 = 0u, u3 = 0u;
      if (g == 0) {              // k0..7: ohx ohy ohz ohx ohy ohz olx oly
        const unsigned ohx = bhi(o.x), ohy = bhi(o.y), ohz = bhi(o.z);
        const unsigned olx = bhi(bres(o.x, ohx));
        const unsigned oly = bhi(bres(o.y, ohy));
        u0 = ohx | (ohy << 16);
        u1 = ohz | (ohx << 16);
        u2 = ohy | (ohz << 16);
        u3 = olx | (oly << 16);
      } else if (g == 1) {       // k8..15: olz 1 1 o2h o2l 0 0 0
        const unsigned ohz = bhi(o.z);
        const unsigned olz = bhi(bres(o.z, ohz));
        const float o2p = o.w + 1.0f;            // +1 bias keeps d2' > 0
        const unsigned o2h = bhi(o2p);
        const unsigned o2l = bhi(bres(o2p, o2h));
        u0 = olz | (0x3F80u << 16);
        u1 = 0x3F80u | (o2h << 16);
        u2 = o2l;
        u3 = 0u;
      }
      bw[j].u = make_uint4(u0, u1, u2, u3);
    }

    unsigned om[NTO];
    #pragma unroll
    for (int j = 0; j < NTO; ++j) om[j] = 0xFFFFFFFFu;

    float* hpart = ws + HP_OFF + (size_t)(((chunk * 2) + set) * B + b) * P1PAD;
    const f32x4 czero = {0.f, 0.f, 0.f, 0.f};
    const int nt = (NTH - wv + 3) >> 2;          // wave0: 13, waves1-3: 12

    for (int s = 0; s < nt; ++s) {
      const int t = wv + 4 * s;
      const int ib = t * 16 + g * 4;
      // ---- JIT A-frag from sVerts (lanes 0-31; lanes 32-63 = zero K) ----
      U4 ac;
      if (l < 32) {
        const float4 v = sm.d2.sVerts[t * 16 + cl];
        if (g == 0) {            // k0..7: hhx hhy hhz hlx hly hlz hhx hhy
          const float sx = -2.f * v.x, sy = -2.f * v.y, sz = -2.f * v.z;
          const unsigned hx = bhi(sx), hy = bhi(sy), hz = bhi(sz);
          const unsigned lx = bhi(bres(sx, hx));
          const unsigned ly = bhi(bres(sy, hy));
          const unsigned lz = bhi(bres(sz, hz));
          ac.u = make_uint4(hx | (hy << 16), hz | (lx << 16),
                            ly | (lz << 16), hx | (hy << 16));
        } else {                 // k8..15: hhz h2h h2l 1 1 0 0 0
          const float sz = -2.f * v.z;
          const unsigned hz = bhi(sz);
          const unsigned h2h = bhi(v.w);
          const unsigned h2l = bhi(bres(v.w, h2h));
          ac.u = make_uint4(hz | (h2h << 16), h2l | (0x3F80u << 16), 0x3F80u, 0u);
        }
      } else {
        ac.u = make_uint4(0u, 0u, 0u, 0u);
      }
      float hm0 = 3.0e38f, hm1 = 3.0e38f, hm2 = 3.0e38f, hm3 = 3.0e38f;
      #pragma unroll
      for (int hs = 0; hs < 2; ++hs) {
        f32x4 dd[NTOH];
        #pragma unroll
        for (int j = 0; j < NTOH; ++j)
          dd[j] = __builtin_amdgcn_mfma_f32_16x16x32_bf16(ac.v, bw[hs * NTOH + j].v, czero, 0, 0, 0);
        #pragma unroll
        for (int j = 0; j < NTOH; ++j) {
          const f32x4 d = dd[j];
          hm0 = fminf(hm0, d[0]); hm1 = fminf(hm1, d[1]);
          hm2 = fminf(hm2, d[2]); hm3 = fminf(hm3, d[3]);
          const unsigned k0 = (__float_as_uint(d[0]) & 0xFFFFFC00u) | (unsigned)(ib + 0);
          const unsigned k1 = (__float_as_uint(d[1]) & 0xFFFFFC00u) | (unsigned)(ib + 1);
          const unsigned k2 = (__float_as_uint(d[2]) & 0xFFFFFC00u) | (unsigned)(ib + 2);
          const unsigned k3 = (__float_as_uint(d[3]) & 0xFFFFFC00u) | (unsigned)(ib + 3);
          om[hs * NTOH + j] = umin2(umin2(umin2(umin2(k0, k1), k2), k3), om[hs * NTOH + j]);
        }
      }
      // h2o: DPP min-reduce across the 16 cols
      hm0 = row_min16(hm0);
      hm1 = row_min16(hm1);
      hm2 = row_min16(hm2);
      hm3 = row_min16(hm3);
      if (cl == 0)
        *(float4*)&hpart[ib] = make_float4(hm0 - 1.f, hm1 - 1.f, hm2 - 1.f, hm3 - 1.f);
    }

    // ---- o2h: fold 4 row-groups in-wave, publish per-wave keys ----
    #pragma unroll
    for (int j = 0; j < NTO; ++j) {
      unsigned v = umin2(om[j], (unsigned)__shfl_xor((int)om[j], 16, 64));
      v = umin2(v, (unsigned)__shfl_xor((int)v, 32, 64));
      if (l < 16) sm.d2.sKeys[wv][j * 16 + l] = v;
    }
    __syncthreads();

    // ---- epilogue: fold 4 waves, store WINNING KEY (sign/sqrt moved to kd3) --
    unsigned* os = (unsigned*)(ws + OS_OFF) + (size_t)(set * B + b) * P2;
    for (int i = tid; i < CHO; i += 256) {
      const int q = chunk * CHO + i;
      if (q < P2)
        os[q] = umin2(umin2(sm.d2.sKeys[0][i], sm.d2.sKeys[1][i]),
                      umin2(sm.d2.sKeys[2][i], sm.d2.sKeys[3][i]));
    }

  } else if (bid < M_D2 + M_NRM) {
    // ================= normals: quarter face-split (R7 form, 2 LDS banks) ====
    const int t = bid - M_D2;
    const int q = t >> 6, r = t & 63, set = r >> 5, b = r & 31;
    const float* verts = (set == 0 ? recon_xyz : hand_xyz) + b * P1 * 3;
    const int* f = faces + b * NF * 3 + q * QF * 3;
    const int nf = (q < 3) ? QF : (NF - 3 * QF);
    for (int i = tid; i < P1; i += 256)
      sm.d1.sv[i] = make_float4(verts[3*i], verts[3*i+1], verts[3*i+2], 0.f);
    for (int i = tid; i < 2 * 2336; i += 256) ((float*)sm.d1.sn)[i] = 0.f;
    __syncthreads();
    float* s = sm.d1.sn[tid >> 7];    // 2 banks: waves {0,1} and {2,3}
    for (int k = tid; k < nf; k += 256) {
      int i0 = f[3*k], i1 = f[3*k+1], i2 = f[3*k+2];
      float4 v0 = sm.d1.sv[i0], v1 = sm.d1.sv[i1], v2 = sm.d1.sv[i2];
      float e0x = v1.x - v0.x, e0y = v1.y - v0.y, e0z = v1.z - v0.z;
      float e1x = v2.x - v0.x, e1y = v2.y - v0.y, e1z = v2.z - v0.z;
      float fx = e0y * e1z - e0z * e1y;
      float fy = e0z * e1x - e0x * e1z;
      float fz = e0x * e1y - e0y * e1x;
      atomicAdd(&s[3*i0+0], fx); atomicAdd(&s[3*i0+1], fy); atomicAdd(&s[3*i0+2], fz);
      atomicAdd(&s[3*i1+0], fx); atomicAdd(&s[3*i1+1], fy); atomicAdd(&s[3*i1+2], fz);
      atomicAdd(&s[3*i2+0], fx); atomicAdd(&s[3*i2+1], fy); atomicAdd(&s[3*i2+2], fz);
    }
    __syncthreads();
    // store RAW quarter-partial sums (sign is scale-invariant)
    float4* np = (float4*)(ws + NP_OFF) + (size_t)((q * 2 + set) * B + b) * P1;
    for (int p = tid; p < P1; p += 256) {
      float nx = sm.d1.sn[0][3*p]   + sm.d1.sn[1][3*p];
      float ny = sm.d1.sn[0][3*p+1] + sm.d1.sn[1][3*p+1];
      float nz = sm.d1.sn[0][3*p+2] + sm.d1.sn[1][3*p+2];
      np[p] = make_float4(nx, ny, nz, 0.f);
    }
  } else {
    // ================= red1: input reductions ================================
    const int blk = bid - M_D2 - M_NRM;
    if (blk == 0 && tid == 0) ((int*)(ws + CNT_OFF))[0] = 0;   // zero kd3 ticket
    const int gtid = blk * 256 + tid, stride = RED1_BLKS * 256;
    float sp = 0.f, sr = 0.f, sk = 0.f;
    for (int i = gtid; i < B * PARAM_DIM; i += stride) { float d = recon_x[i] - x[i]; sp += d * d; }
    for (int i = gtid; i < B * P1 * 3; i += stride)    { float d = recon_xyz[i] - hand_xyz[i]; sr += d * d; }
    for (int i = gtid; i < B * LATENT; i += stride)    { float lv = logvar[i], m = mu[i]; sk += 1.f + lv - m * m - expf(lv); }
    for (int off = 32; off > 0; off >>= 1) {
      sp += __shfl_down(sp, off, 64);
      sr += __shfl_down(sr, off, 64);
      sk += __shfl_down(sk, off, 64);
    }
    float* sred = (float*)sm.d1.sn;
    const int wv = tid >> 6;
    if ((tid & 63) == 0) { sred[wv*3] = sp; sred[wv*3+1] = sr; sred[wv*3+2] = sk; }
    __syncthreads();
    if (tid == 0) {
      float a = 0.f, bb = 0.f, c = 0.f;
      for (int w = 0; w < 4; ++w) { a += sred[w*3]; bb += sred[w*3+1]; c += sred[w*3+2]; }
      ws[R1_OFF + blk*3+0] = a; ws[R1_OFF + blk*3+1] = bb; ws[R1_OFF + blk*3+2] = c;
    }
  }
}

// ---------------- D2: o-combine (sign recompute) ∥ h-combine + finalize ------
__global__ __launch_bounds__(256) void kd3(
    const float* __restrict__ vw,
    const float* __restrict__ recon_xyz, const float* __restrict__ hand_xyz,
    const float* __restrict__ obj,
    float* __restrict__ ws, float* __restrict__ out) {
  __shared__ float sred[4];
  __shared__ int lastFlag;
  const int tid = threadIdx.x;
  const int bid = blockIdx.x;
  if (bid < OC_BLKS) {
    const unsigned* osu = (const unsigned*)(ws + OS_OFF);
    const float4* npb = (const float4*)(ws + NP_OFF);
    const int gtid = bid * 256 + tid, stride = OC_BLKS * 256;
    float so = 0.f;
    for (int i = gtid; i < B * P2; i += stride) {
      const int b = i / P2, q = i - b * P2;
      int hiA = (int)(osu[i] & 1023u);                  if (hiA > P1-1) hiA = P1-1;
      int hiB = (int)(osu[(size_t)B * P2 + i] & 1023u); if (hiB > P1-1) hiB = P1-1;
      const float* op = obj + ((size_t)b * P2 + q) * 3;
      const float ox = op[0], oy = op[1], oz = op[2];
      const float* va = recon_xyz + ((size_t)b * P1 + hiA) * 3;
      const float* vb = hand_xyz  + ((size_t)b * P1 + hiB) * 3;
      const float dxA = ox - va[0], dyA = oy - va[1], dzA = oz - va[2];
      const float dxB = ox - vb[0], dyB = oy - vb[1], dzB = oz - vb[2];
      const float d2A = fmaf(dxA, dxA, fmaf(dyA, dyA, dzA * dzA));
      const float d2B = fmaf(dxB, dxB, fmaf(dyB, dyB, dzB * dzB));
      // sum the 4 quarter-partial normal planes per set
      float nAx = 0.f, nAy = 0.f, nAz = 0.f, nBx = 0.f, nBy = 0.f, nBz = 0.f;
      #pragma unroll
      for (int qt = 0; qt < 4; ++qt) {
        const float4 na = npb[(size_t)((qt * 2 + 0) * B + b) * P1 + hiA];
        const float4 nb = npb[(size_t)((qt * 2 + 1) * B + b) * P1 + hiB];
        nAx += na.x; nAy += na.y; nAz += na.z;
        nBx += nb.x; nBy += nb.y; nBz += nb.z;
      }
      const float dtA = nAx * dxA + nAy * dyA + nAz * dzA;
      const float dtB = nBx * dxB + nBy * dyB + nBz * dzB;
      const float sgA = (dtA > 0.f) ? 1.f : ((dtA < 0.f) ? -1.f : 0.f);
      const float sgB = (dtB > 0.f) ? 1.f : ((dtB < 0.f) ? -1.f : 0.f);
      const float osA = sqrtf(d2A) * sgA;
      const float osB = sqrtf(d2B) * sgB;
      bool wdist = (osB < 0.01f) && (osB > -0.005f);
      float w = (osA < 0.f) ? 1.5f : (wdist ? 1.f : 0.1f);
      so += fabsf(osA - osB) * w;
    }
    for (int off = 32; off > 0; off >>= 1) so += __shfl_down(so, off, 64);
    if ((tid & 63) == 0) sred[tid >> 6] = so;
    __syncthreads();
    if (tid == 0) ws[RO_OFF + bid] = sred[0] + sred[1] + sred[2] + sred[3];
  } else {
    const int blk = bid - OC_BLKS;
    const int gtid = blk * 256 + tid, stride = HC_BLKS * 256;
    float sh = 0.f;
    for (int i = gtid; i < B * P1; i += stride) {
      const int p = i % P1, bb = i / P1;
      const size_t base0 = (size_t)HP_OFF + (size_t)bb * P1PAD + p;
      float m0 = 3.0e38f, m1 = 3.0e38f;
      #pragma unroll
      for (int c = 0; c < NPART; ++c) {
        m0 = fminf(m0, ws[base0 + (size_t)(c*2+0) * B * P1PAD]);
        m1 = fminf(m1, ws[base0 + (size_t)(c*2+1) * B * P1PAD]);
      }
      m0 = fmaxf(m0, 0.f); m1 = fmaxf(m1, 0.f);
      sh += fabsf(sqrtf(m0) - sqrtf(m1)) * powf(vw[p], 0.4f);
    }
    for (int off = 32; off > 0; off >>= 1) sh += __shfl_down(sh, off, 64);
    if ((tid & 63) == 0) sred[tid >> 6] = sh;
    __syncthreads();
    if (tid == 0) ws[RH_OFF + blk] = sred[0] + sred[1] + sred[2] + sred[3];
  }

  // ---- last-block ticket: winner does the (tiny) final reduction ----
  __threadfence();                               // release our partial
  if (tid == 0) {
    const int t = atomicAdd((int*)(ws + CNT_OFF), 1);
    lastFlag = (t == D3_TOT - 1);
  }
  __syncthreads();
  if (lastFlag) {
    __threadfence();                             // acquire peers' partials
    if (tid < 64) {
      const int lane = tid;
      float sp = 0.f, sr = 0.f, sk = 0.f, sh = 0.f, so = 0.f;
      for (int i = lane; i < RED1_BLKS; i += 64) {
        sp += ws[R1_OFF + i*3+0]; sr += ws[R1_OFF + i*3+1]; sk += ws[R1_OFF + i*3+2];
      }
      for (int i = lane; i < HC_BLKS; i += 64) sh += ws[RH_OFF + i];
      for (int i = lane; i < OC_BLKS; i += 64) so += ws[RO_OFF + i];
      for (int off = 32; off > 0; off >>= 1) {
        sp += __shfl_down(sp, off, 64);
        sr += __shfl_down(sr, off, 64);
        sk += __shfl_down(sk, off, 64);
        sh += __shfl_down(sh, off, 64);
        so += __shfl_down(so, off, 64);
      }
      if (lane == 0) {
        float param_loss = sp / (float)B;
        float recon_loss = sr / (float)B;
        float KLD = -0.5f * sk / (float)B;
        float cvae = recon_loss + KLD;
        float loss_h = 35.f * (1.f - 0.005f) * sh / (float)(B * P1);
        float loss_o = 30.f * (1.f - 0.005f) * so / (float)(B * P2);
        float ho = loss_h + loss_o;
        out[0] = cvae + 0.1f * param_loss + 10.f * ho;
        out[1] = param_loss;
        out[2] = ho;
        out[3] = recon_loss;
        out[4] = KLD;
      }
    }
  }
}

extern "C" void kernel_launch(void* const* d_in, const int* in_sizes, int n_in,
                              void* d_out, int out_size, void* d_ws, size_t ws_size,
                              hipStream_t stream) {
  const float* recon_x   = (const float*)d_in[0];
  const float* x         = (const float*)d_in[1];
  const float* mu        = (const float*)d_in[2];
  const float* logvar    = (const float*)d_in[3];
  const float* recon_xyz = (const float*)d_in[4];
  const float* hand_xyz  = (const float*)d_in[5];
  const int*   faces     = (const int*)d_in[6];
  const float* obj       = (const float*)d_in[7];
  const float* vw        = (const float*)d_in[8];
  float* ws = (float*)d_ws;
  float* out = (float*)d_out;

  kd12<<<dim3(M_TOT), 256, 0, stream>>>(recon_x, x, mu, logvar,
                                        recon_xyz, hand_xyz, faces, obj, ws);
  kd3<<<dim3(D3_TOT), 256, 0, stream>>>(vw, recon_xyz, hand_xyz, obj, ws, out);
}

// Round 10
// 138.784 us; speedup vs baseline: 1.0582x; 1.0582x over previous
//
#include <hip/hip_runtime.h>
#include <math.h>

#define B 32
#define P1 778
#define NF 1538
#define P2 3000
#define PARAM_DIM 61
#define LATENT 64

// ---- MFMA kd2 geometry ----
#define P1PAD 784            // 49 hand tiles of 16
#define NTH 49               // hand tiles
#define CHO 192              // obj pts per block (16 chunks cover 3000..3072)
#define NTO 12               // obj tiles (of 16) per block; all waves sweep all 12
#define NTOH 6               // MFMA cluster depth (dd[] register budget)
#define NCH 16               // obj chunks -> grid 1024 = 4 blocks/CU
#define NPART NCH            // h2o partial sets per (set,b)

#define RED1_BLKS 16
#define HC_BLKS 128
#define OC_BLKS 192
#define QF 385               // faces per quarter-split (3*385 + 383 = 1538)

#define D1_NRM 256           // 4 quarters * 2 sets * 32 batches
#define D1_TOT (D1_NRM + RED1_BLKS)
#define D2_TOT (NCH * 64)    // 1024 blocks
#define D3_TOT (OC_BLKS + HC_BLKS)

// ws layout (float offsets)
#define NP_OFF  0
#define NP_SZ   (4*2*B*P1*4)           // [quarter*2+set][b][p] float4 raw normals
#define OS_OFF  (NP_OFF + NP_SZ)       // signed o2h distances (float)
#define OS_SZ   (2*B*P2)
#define HP_OFF  (OS_OFF + OS_SZ)
#define HP_SZ   (NPART*2*B*P1PAD)
#define R1_OFF  (HP_OFF + HP_SZ)
#define RH_OFF  (R1_OFF + RED1_BLKS*3)
#define RO_OFF  (RH_OFF + HC_BLKS)
#define CNT_OFF (RO_OFF + OC_BLKS)     // kd3 completion ticket (zeroed by kd1)

typedef __attribute__((ext_vector_type(8))) short bf16x8;
typedef __attribute__((ext_vector_type(4))) float f32x4;
union U4 { uint4 u; bf16x8 v; };

static __device__ __forceinline__ unsigned umin2(unsigned a, unsigned b) { return a < b ? a : b; }
// top 16 bits of an f32 = bf16 by truncation (residual stays exactly representable)
static __device__ __forceinline__ unsigned bhi(float x) { return __float_as_uint(x) >> 16; }
static __device__ __forceinline__ float bres(float x, unsigned h) { return x - __uint_as_float(h << 16); }

// DPP min-reduce stage across a 16-lane row (no DS pipe, no waitcnt).
// CTRL: 0xB1 = quad_perm[1,0,3,2], 0x4E = quad_perm[2,3,0,1],
//       0x124 = row_ror:4, 0x128 = row_ror:8. Rotation valid for commutative min.
template <int CTRL>
static __device__ __forceinline__ float dpp_min(float x) {
  const int xi = __float_as_int(x);
  const int yi = __builtin_amdgcn_update_dpp(xi, xi, CTRL, 0xF, 0xF, false);
  return fminf(x, __int_as_float(yi));
}
static __device__ __forceinline__ float row_min16(float x) {
  x = dpp_min<0xB1>(x);
  x = dpp_min<0x4E>(x);
  x = dpp_min<0x124>(x);
  x = dpp_min<0x128>(x);
  return x;
}

// ---------------- D1: raw vertex-normal partials (4 blocks/mesh) + red1 ------
__global__ __launch_bounds__(256) void kd1(
    const float* __restrict__ recon_x, const float* __restrict__ x,
    const float* __restrict__ mu, const float* __restrict__ logvar,
    const float* __restrict__ recon_xyz, const float* __restrict__ hand_xyz,
    const int* __restrict__ faces, float* __restrict__ ws) {
  __shared__ float4 sv[P1];           // 12448 B
  __shared__ float sn[4][2336];       // wave-private accumulators, 37376 B
  const int tid = threadIdx.x;
  const int bid = blockIdx.x;

  if (bid < D1_NRM) {
    const int q = bid >> 6, r = bid & 63, set = r >> 5, b = r & 31;
    const float* verts = (set == 0 ? recon_xyz : hand_xyz) + b * P1 * 3;
    const int* f = faces + b * NF * 3 + q * QF * 3;
    const int nf = (q < 3) ? QF : (NF - 3 * QF);
    for (int i = tid; i < P1; i += 256)
      sv[i] = make_float4(verts[3*i], verts[3*i+1], verts[3*i+2], 0.f);
    for (int i = tid; i < 4 * 2336; i += 256) ((float*)sn)[i] = 0.f;
    __syncthreads();
    float* s = sn[tid >> 6];          // wave-private: no cross-wave contention
    for (int k = tid; k < nf; k += 256) {
      int i0 = f[3*k], i1 = f[3*k+1], i2 = f[3*k+2];
      float4 v0 = sv[i0], v1 = sv[i1], v2 = sv[i2];
      float e0x = v1.x - v0.x, e0y = v1.y - v0.y, e0z = v1.z - v0.z;
      float e1x = v2.x - v0.x, e1y = v2.y - v0.y, e1z = v2.z - v0.z;
      float fx = e0y * e1z - e0z * e1y;
      float fy = e0z * e1x - e0x * e1z;
      float fz = e0x * e1y - e0y * e1x;
      atomicAdd(&s[3*i0+0], fx); atomicAdd(&s[3*i0+1], fy); atomicAdd(&s[3*i0+2], fz);
      atomicAdd(&s[3*i1+0], fx); atomicAdd(&s[3*i1+1], fy); atomicAdd(&s[3*i1+2], fz);
      atomicAdd(&s[3*i2+0], fx); atomicAdd(&s[3*i2+1], fy); atomicAdd(&s[3*i2+2], fz);
    }
    __syncthreads();
    // sign(n.v) is invariant under positive scaling -> store RAW sums, no normalize
    float4* np = (float4*)(ws + NP_OFF) + (size_t)((q * 2 + set) * B + b) * P1;
    for (int p = tid; p < P1; p += 256) {
      float nx = sn[0][3*p] + sn[1][3*p] + sn[2][3*p] + sn[3][3*p];
      float ny = sn[0][3*p+1] + sn[1][3*p+1] + sn[2][3*p+1] + sn[3][3*p+1];
      float nz = sn[0][3*p+2] + sn[1][3*p+2] + sn[2][3*p+2] + sn[3][3*p+2];
      np[p] = make_float4(nx, ny, nz, 0.f);
    }
  } else {
    const int blk = bid - D1_NRM;
    if (blk == 0 && tid == 0) ((int*)(ws + CNT_OFF))[0] = 0;   // zero kd3 ticket
    const int gtid = blk * 256 + tid, stride = RED1_BLKS * 256;
    float sp = 0.f, sr = 0.f, sk = 0.f;
    for (int i = gtid; i < B * PARAM_DIM; i += stride) { float d = recon_x[i] - x[i]; sp += d * d; }
    for (int i = gtid; i < B * P1 * 3; i += stride)    { float d = recon_xyz[i] - hand_xyz[i]; sr += d * d; }
    for (int i = gtid; i < B * LATENT; i += stride)    { float lv = logvar[i], m = mu[i]; sk += 1.f + lv - m * m - expf(lv); }
    for (int off = 32; off > 0; off >>= 1) {
      sp += __shfl_down(sp, off, 64);
      sr += __shfl_down(sr, off, 64);
      sk += __shfl_down(sk, off, 64);
    }
    float* sred = (float*)sn;
    const int wv = tid >> 6;
    if ((tid & 63) == 0) { sred[wv*3] = sp; sred[wv*3+1] = sr; sred[wv*3+2] = sk; }
    __syncthreads();
    if (tid == 0) {
      float a = 0.f, bb = 0.f, c = 0.f;
      for (int w = 0; w < 4; ++w) { a += sred[w*3]; bb += sred[w*3+1]; c += sred[w*3+2]; }
      ws[R1_OFF + blk*3+0] = a; ws[R1_OFF + blk*3+1] = bb; ws[R1_OFF + blk*3+2] = c;
    }
  }
}

// ---------------- D2: fused o2h + h2o via MFMA distance tiles ----------------
// Grid: (chunk of 192 obj pts, set, b) = 16*2*32 = 1024 blocks, 4 blocks/CU.
// Waves split the 49 hand tiles (13/12/12/12); every wave sweeps all 12 obj
// tiles of the chunk (B-frags in registers). A-frags built JIT from the LDS
// vert tile. h2o per-tile 16-lane reduce via DPP. Signed-distance epilogue
// stays HERE (sVerts in LDS + 4-plane NP reads at 1024-block occupancy —
// moving it to kd3 cost 40 us of exposed latency, R9).
__global__ __launch_bounds__(256, 4) void kd2(
    const float* __restrict__ recon_xyz, const float* __restrict__ hand_xyz,
    const float* __restrict__ obj, float* __restrict__ ws) {
  __shared__ float4 sVerts[P1PAD];             // 12544 B (xyz, w=|h|^2)
  __shared__ float4 sObj[CHO];                 // 3072 B (xyz, w=|o|^2)
  __shared__ unsigned sKeys[4][CHO];           // 3072 B per-wave o2h keys

  const int tid = threadIdx.x;
  const int bid = blockIdx.x;
  const int chunk = bid >> 6, rr = bid & 63, set = rr >> 5, b = rr & 31;
  const float* verts = (set == 0 ? recon_xyz : hand_xyz) + b * P1 * 3;
  const float* op = obj + (size_t)b * P2 * 3;

  for (int i = tid; i < P1PAD; i += 256) {
    float vx, vy, vz;
    if (i < P1) { vx = verts[3*i]; vy = verts[3*i+1]; vz = verts[3*i+2]; }
    else        { vx = vy = vz = 1.0e6f; }     // far pad row: never argmin
    sVerts[i] = make_float4(vx, vy, vz, vx*vx + vy*vy + vz*vz);
  }
  for (int i = tid; i < CHO; i += 256) {
    const int q = chunk * CHO + i;
    float ox, oy, oz;
    if (q < P2) { ox = op[3*q]; oy = op[3*q+1]; oz = op[3*q+2]; }
    else        { ox = oy = oz = 1.0e6f; }     // pad: huge d2, never wins, discarded
    sObj[i] = make_float4(ox, oy, oz, ox*ox + oy*oy + oz*oz);
  }
  __syncthreads();

  // ---- pack B fragments (obj side) into registers, identical per wave ----
  const int l = tid & 63, wv = tid >> 6, g = l >> 4, cl = l & 15;
  U4 bw[NTO];
  #pragma unroll
  for (int j = 0; j < NTO; ++j) {
    const float4 o = sObj[j * 16 + cl];
    unsigned u0 = 0u, u1 = 0u, u2 = 0u, u3 = 0u;
    if (g == 0) {              // k0..7: ohx ohy ohz ohx ohy ohz olx oly
      const unsigned ohx = bhi(o.x), ohy = bhi(o.y), ohz = bhi(o.z);
      const unsigned olx = bhi(bres(o.x, ohx));
      const unsigned oly = bhi(bres(o.y, ohy));
      u0 = ohx | (ohy << 16);
      u1 = ohz | (ohx << 16);
      u2 = ohy | (ohz << 16);
      u3 = olx | (oly << 16);
    } else if (g == 1) {       // k8..15: olz 1 1 o2h o2l 0 0 0
      const unsigned ohz = bhi(o.z);
      const unsigned olz = bhi(bres(o.z, ohz));
      const float o2p = o.w + 1.0f;            // +1 bias keeps d2' > 0 for key-min
      const unsigned o2h = bhi(o2p);
      const unsigned o2l = bhi(bres(o2p, o2h));
      u0 = olz | (0x3F80u << 16);
      u1 = 0x3F80u | (o2h << 16);
      u2 = o2l;
      u3 = 0u;
    }
    bw[j].u = make_uint4(u0, u1, u2, u3);
  }

  // ---- main sweep: this wave's hand tiles (t = wv, wv+4, ...) x 12 obj tiles
  unsigned om[NTO];
  #pragma unroll
  for (int j = 0; j < NTO; ++j) om[j] = 0xFFFFFFFFu;

  float* hpart = ws + HP_OFF + (size_t)(((chunk * 2) + set) * B + b) * P1PAD;
  const f32x4 czero = {0.f, 0.f, 0.f, 0.f};
  const int nt = (NTH - wv + 3) >> 2;          // wave0: 13, waves1-3: 12

  for (int s = 0; s < nt; ++s) {
    const int t = wv + 4 * s;
    const int ib = t * 16 + g * 4;             // this lane's hand-row base
    // ---- JIT A-frag from sVerts (lanes 0-31; lanes 32-63 carry k16-31 = 0) --
    U4 ac;
    if (l < 32) {
      const float4 v = sVerts[t * 16 + cl];
      if (g == 0) {            // k0..7: hhx hhy hhz hlx hly hlz hhx hhy
        const float sx = -2.f * v.x, sy = -2.f * v.y, sz = -2.f * v.z;
        const unsigned hx = bhi(sx), hy = bhi(sy), hz = bhi(sz);
        const unsigned lx = bhi(bres(sx, hx));
        const unsigned ly = bhi(bres(sy, hy));
        const unsigned lz = bhi(bres(sz, hz));
        ac.u = make_uint4(hx | (hy << 16), hz | (lx << 16),
                          ly | (lz << 16), hx | (hy << 16));
      } else {                 // k8..15: hhz h2h h2l 1 1 0 0 0
        const float sz = -2.f * v.z;
        const unsigned hz = bhi(sz);
        const unsigned h2h = bhi(v.w);
        const unsigned h2l = bhi(bres(v.w, h2h));
        ac.u = make_uint4(hz | (h2h << 16), h2l | (0x3F80u << 16), 0x3F80u, 0u);
      }
    } else {
      ac.u = make_uint4(0u, 0u, 0u, 0u);
    }
    float hm0 = 3.0e38f, hm1 = 3.0e38f, hm2 = 3.0e38f, hm3 = 3.0e38f;
    // ---- two half-sweeps: issue NTOH independent MFMAs, then consume ----
    #pragma unroll
    for (int hs = 0; hs < 2; ++hs) {
      f32x4 dd[NTOH];
      #pragma unroll
      for (int j = 0; j < NTOH; ++j)
        dd[j] = __builtin_amdgcn_mfma_f32_16x16x32_bf16(ac.v, bw[hs * NTOH + j].v, czero, 0, 0, 0);
      #pragma unroll
      for (int j = 0; j < NTOH; ++j) {
        const f32x4 d = dd[j];
        hm0 = fminf(hm0, d[0]); hm1 = fminf(hm1, d[1]);
        hm2 = fminf(hm2, d[2]); hm3 = fminf(hm3, d[3]);
        // left-chained so clang emits v_and_or_b32 + v_min3_u32 pairs
        const unsigned k0 = (__float_as_uint(d[0]) & 0xFFFFFC00u) | (unsigned)(ib + 0);
        const unsigned k1 = (__float_as_uint(d[1]) & 0xFFFFFC00u) | (unsigned)(ib + 1);
        const unsigned k2 = (__float_as_uint(d[2]) & 0xFFFFFC00u) | (unsigned)(ib + 2);
        const unsigned k3 = (__float_as_uint(d[3]) & 0xFFFFFC00u) | (unsigned)(ib + 3);
        om[hs * NTOH + j] = umin2(umin2(umin2(umin2(k0, k1), k2), k3), om[hs * NTOH + j]);
      }
    }
    // h2o: DPP min-reduce across the 16 cols (contiguous lanes sharing g)
    hm0 = row_min16(hm0);
    hm1 = row_min16(hm1);
    hm2 = row_min16(hm2);
    hm3 = row_min16(hm3);
    if (cl == 0)
      *(float4*)&hpart[ib] = make_float4(hm0 - 1.f, hm1 - 1.f, hm2 - 1.f, hm3 - 1.f);
  }

  // ---- o2h: fold the 4 row-groups within the wave, publish per-wave keys ----
  #pragma unroll
  for (int j = 0; j < NTO; ++j) {
    unsigned v = umin2(om[j], (unsigned)__shfl_xor((int)om[j], 16, 64));
    v = umin2(v, (unsigned)__shfl_xor((int)v, 32, 64));
    if (l < 16) sKeys[wv][j * 16 + l] = v;
  }
  __syncthreads();

  // ---- o2h epilogue: fold 4 waves, exact recompute + sign from raw normals --
  const float4* npb = (const float4*)(ws + NP_OFF);
  float* os = ws + OS_OFF + (size_t)(set * B + b) * P2;
  for (int i = tid; i < CHO; i += 256) {
    const int q = chunk * CHO + i;
    if (q < P2) {
      const unsigned key = umin2(umin2(sKeys[0][i], sKeys[1][i]),
                                 umin2(sKeys[2][i], sKeys[3][i]));
      int hi = (int)(key & 1023u); if (hi > P1 - 1) hi = P1 - 1;
      const float4 h = sVerts[hi];
      const float4 o = sObj[i];
      const float dx = o.x - h.x, dy = o.y - h.y, dz = o.z - h.z;
      const float d2 = fmaf(dx, dx, fmaf(dy, dy, dz * dz));
      const float4 n0 = npb[(size_t)((0 * 2 + set) * B + b) * P1 + hi];
      const float4 n1 = npb[(size_t)((1 * 2 + set) * B + b) * P1 + hi];
      const float4 n2 = npb[(size_t)((2 * 2 + set) * B + b) * P1 + hi];
      const float4 n3 = npb[(size_t)((3 * 2 + set) * B + b) * P1 + hi];
      const float nx = (n0.x + n1.x) + (n2.x + n3.x);
      const float ny = (n0.y + n1.y) + (n2.y + n3.y);
      const float nz = (n0.z + n1.z) + (n2.z + n3.z);
      const float dt = nx * dx + ny * dy + nz * dz;
      const float sg = (dt > 0.f) ? 1.f : ((dt < 0.f) ? -1.f : 0.f);
      os[q] = sqrtf(d2) * sg;
    }
  }
}

// ---------------- D3: o-combine ∥ h-combine + fused finalize -----------------
__global__ __launch_bounds__(256) void kd3(const float* __restrict__ vw,
                                           float* __restrict__ ws,
                                           float* __restrict__ out) {
  __shared__ float sred[4];
  __shared__ int lastFlag;
  const int tid = threadIdx.x;
  const int bid = blockIdx.x;
  if (bid < OC_BLKS) {
    const int gtid = bid * 256 + tid, stride = OC_BLKS * 256;
    float so = 0.f;
    for (int i = gtid; i < B * P2; i += stride) {
      float osA = ws[OS_OFF + i];
      float osB = ws[OS_OFF + (size_t)B * P2 + i];
      bool wdist = (osB < 0.01f) && (osB > -0.005f);
      float w = (osA < 0.f) ? 1.5f : (wdist ? 1.f : 0.1f);
      so += fabsf(osA - osB) * w;
    }
    for (int off = 32; off > 0; off >>= 1) so += __shfl_down(so, off, 64);
    if ((tid & 63) == 0) sred[tid >> 6] = so;
    __syncthreads();
    if (tid == 0) ws[RO_OFF + bid] = sred[0] + sred[1] + sred[2] + sred[3];
  } else {
    const int blk = bid - OC_BLKS;
    const int gtid = blk * 256 + tid, stride = HC_BLKS * 256;
    float sh = 0.f;
    for (int i = gtid; i < B * P1; i += stride) {
      const int p = i % P1, bb = i / P1;
      const size_t base0 = (size_t)HP_OFF + (size_t)bb * P1PAD + p;
      float m0 = 3.0e38f, m1 = 3.0e38f;
      #pragma unroll
      for (int c = 0; c < NPART; ++c) {
        m0 = fminf(m0, ws[base0 + (size_t)(c*2+0) * B * P1PAD]);
        m1 = fminf(m1, ws[base0 + (size_t)(c*2+1) * B * P1PAD]);
      }
      m0 = fmaxf(m0, 0.f); m1 = fmaxf(m1, 0.f);
      sh += fabsf(sqrtf(m0) - sqrtf(m1)) * powf(vw[p], 0.4f);
    }
    for (int off = 32; off > 0; off >>= 1) sh += __shfl_down(sh, off, 64);
    if ((tid & 63) == 0) sred[tid >> 6] = sh;
    __syncthreads();
    if (tid == 0) ws[RH_OFF + blk] = sred[0] + sred[1] + sred[2] + sred[3];
  }

  // ---- last-block ticket: winner does the (tiny) final reduction ----
  __threadfence();                               // release our partial
  if (tid == 0) {
    const int t = atomicAdd((int*)(ws + CNT_OFF), 1);
    lastFlag = (t == D3_TOT - 1);
  }
  __syncthreads();
  if (lastFlag) {
    __threadfence();                             // acquire peers' partials
    if (tid < 64) {
      const int lane = tid;
      float sp = 0.f, sr = 0.f, sk = 0.f, sh = 0.f, so = 0.f;
      for (int i = lane; i < RED1_BLKS; i += 64) {
        sp += ws[R1_OFF + i*3+0]; sr += ws[R1_OFF + i*3+1]; sk += ws[R1_OFF + i*3+2];
      }
      for (int i = lane; i < HC_BLKS; i += 64) sh += ws[RH_OFF + i];
      for (int i = lane; i < OC_BLKS; i += 64) so += ws[RO_OFF + i];
      for (int off = 32; off > 0; off >>= 1) {
        sp += __shfl_down(sp, off, 64);
        sr += __shfl_down(sr, off, 64);
        sk += __shfl_down(sk, off, 64);
        sh += __shfl_down(sh, off, 64);
        so += __shfl_down(so, off, 64);
      }
      if (lane == 0) {
        float param_loss = sp / (float)B;
        float recon_loss = sr / (float)B;
        float KLD = -0.5f * sk / (float)B;
        float cvae = recon_loss + KLD;
        float loss_h = 35.f * (1.f - 0.005f) * sh / (float)(B * P1);
        float loss_o = 30.f * (1.f - 0.005f) * so / (float)(B * P2);
        float ho = loss_h + loss_o;
        out[0] = cvae + 0.1f * param_loss + 10.f * ho;
        out[1] = param_loss;
        out[2] = ho;
        out[3] = recon_loss;
        out[4] = KLD;
      }
    }
  }
}

extern "C" void kernel_launch(void* const* d_in, const int* in_sizes, int n_in,
                              void* d_out, int out_size, void* d_ws, size_t ws_size,
                              hipStream_t stream) {
  const float* recon_x   = (const float*)d_in[0];
  const float* x         = (const float*)d_in[1];
  const float* mu        = (const float*)d_in[2];
  const float* logvar    = (const float*)d_in[3];
  const float* recon_xyz = (const float*)d_in[4];
  const float* hand_xyz  = (const float*)d_in[5];
  const int*   faces     = (const int*)d_in[6];
  const float* obj       = (const float*)d_in[7];
  const float* vw        = (const float*)d_in[8];
  float* ws = (float*)d_ws;
  float* out = (float*)d_out;

  kd1<<<dim3(D1_TOT), 256, 0, stream>>>(recon_x, x, mu, logvar,
                                        recon_xyz, hand_xyz, faces, ws);
  kd2<<<dim3(D2_TOT), 256, 0, stream>>>(recon_xyz, hand_xyz, obj, ws);
  kd3<<<dim3(D3_TOT), 256, 0, stream>>>(vw, ws, out);
}

// Round 11
// 116.988 us; speedup vs baseline: 1.2554x; 1.1863x over previous
//
#include <hip/hip_runtime.h>
#include <math.h>

#define B 32
#define P1 778
#define NF 1538
#define P2 3000
#define PARAM_DIM 61
#define LATENT 64

// ---- MFMA kd2 geometry ----
#define P1PAD 784            // 49 hand tiles of 16
#define NTH 49               // hand tiles
#define CHO 192              // obj pts per block (16 chunks cover 3000..3072)
#define NTO 12               // obj tiles (of 16) per block; all waves sweep all 12
#define NTOH 6               // MFMA cluster depth (dd[] register budget)
#define NCH 16               // obj chunks -> grid 1024 = 4 blocks/CU
#define NPART NCH            // h2o partial sets per (set,b)

#define RED1_BLKS 16
#define HC_BLKS 128
#define OC_BLKS 192
#define QF 385               // faces per quarter-split (3*385 + 383 = 1538)

#define D1_NRM 256           // 4 quarters * 2 sets * 32 batches
#define D1_TOT (D1_NRM + RED1_BLKS)
#define D2_TOT (NCH * 64)    // 1024 blocks
#define D3_TOT (OC_BLKS + HC_BLKS)

// ws layout (float offsets)
#define NP_OFF  0
#define NP_SZ   (4*2*B*P1*4)           // [quarter*2+set][b][p] float4 raw normals
#define OS_OFF  (NP_OFF + NP_SZ)       // signed o2h distances (float)
#define OS_SZ   (2*B*P2)
#define HP_OFF  (OS_OFF + OS_SZ)
#define HP_SZ   (NPART*2*B*P1PAD)
#define R1_OFF  (HP_OFF + HP_SZ)
#define RH_OFF  (R1_OFF + RED1_BLKS*3)
#define RO_OFF  (RH_OFF + HC_BLKS)

typedef __attribute__((ext_vector_type(8))) short bf16x8;
typedef __attribute__((ext_vector_type(4))) float f32x4;
union U4 { uint4 u; bf16x8 v; };

static __device__ __forceinline__ unsigned umin2(unsigned a, unsigned b) { return a < b ? a : b; }
// top 16 bits of an f32 = bf16 by truncation (residual stays exactly representable)
static __device__ __forceinline__ unsigned bhi(float x) { return __float_as_uint(x) >> 16; }
static __device__ __forceinline__ float bres(float x, unsigned h) { return x - __uint_as_float(h << 16); }

// DPP min-reduce stage across a 16-lane row (no DS pipe, no waitcnt).
// CTRL: 0xB1 = quad_perm[1,0,3,2], 0x4E = quad_perm[2,3,0,1],
//       0x124 = row_ror:4, 0x128 = row_ror:8. Rotation valid for commutative min.
template <int CTRL>
static __device__ __forceinline__ float dpp_min(float x) {
  const int xi = __float_as_int(x);
  const int yi = __builtin_amdgcn_update_dpp(xi, xi, CTRL, 0xF, 0xF, false);
  return fminf(x, __int_as_float(yi));
}
static __device__ __forceinline__ float row_min16(float x) {
  x = dpp_min<0xB1>(x);
  x = dpp_min<0x4E>(x);
  x = dpp_min<0x124>(x);
  x = dpp_min<0x128>(x);
  return x;
}

// ---------------- D1: raw vertex-normal partials (4 blocks/mesh) + red1 ------
__global__ __launch_bounds__(256) void kd1(
    const float* __restrict__ recon_x, const float* __restrict__ x,
    const float* __restrict__ mu, const float* __restrict__ logvar,
    const float* __restrict__ recon_xyz, const float* __restrict__ hand_xyz,
    const int* __restrict__ faces, float* __restrict__ ws) {
  __shared__ float4 sv[P1];           // 12448 B
  __shared__ float sn[4][2336];       // wave-private accumulators, 37376 B
  const int tid = threadIdx.x;
  const int bid = blockIdx.x;

  if (bid < D1_NRM) {
    const int q = bid >> 6, r = bid & 63, set = r >> 5, b = r & 31;
    const float* verts = (set == 0 ? recon_xyz : hand_xyz) + b * P1 * 3;
    const int* f = faces + b * NF * 3 + q * QF * 3;
    const int nf = (q < 3) ? QF : (NF - 3 * QF);
    for (int i = tid; i < P1; i += 256)
      sv[i] = make_float4(verts[3*i], verts[3*i+1], verts[3*i+2], 0.f);
    for (int i = tid; i < 4 * 2336; i += 256) ((float*)sn)[i] = 0.f;
    __syncthreads();
    float* s = sn[tid >> 6];          // wave-private: no cross-wave contention
    for (int k = tid; k < nf; k += 256) {
      int i0 = f[3*k], i1 = f[3*k+1], i2 = f[3*k+2];
      float4 v0 = sv[i0], v1 = sv[i1], v2 = sv[i2];
      float e0x = v1.x - v0.x, e0y = v1.y - v0.y, e0z = v1.z - v0.z;
      float e1x = v2.x - v0.x, e1y = v2.y - v0.y, e1z = v2.z - v0.z;
      float fx = e0y * e1z - e0z * e1y;
      float fy = e0z * e1x - e0x * e1z;
      float fz = e0x * e1y - e0y * e1x;
      atomicAdd(&s[3*i0+0], fx); atomicAdd(&s[3*i0+1], fy); atomicAdd(&s[3*i0+2], fz);
      atomicAdd(&s[3*i1+0], fx); atomicAdd(&s[3*i1+1], fy); atomicAdd(&s[3*i1+2], fz);
      atomicAdd(&s[3*i2+0], fx); atomicAdd(&s[3*i2+1], fy); atomicAdd(&s[3*i2+2], fz);
    }
    __syncthreads();
    // sign(n.v) is invariant under positive scaling -> store RAW sums, no normalize
    float4* np = (float4*)(ws + NP_OFF) + (size_t)((q * 2 + set) * B + b) * P1;
    for (int p = tid; p < P1; p += 256) {
      float nx = sn[0][3*p] + sn[1][3*p] + sn[2][3*p] + sn[3][3*p];
      float ny = sn[0][3*p+1] + sn[1][3*p+1] + sn[2][3*p+1] + sn[3][3*p+1];
      float nz = sn[0][3*p+2] + sn[1][3*p+2] + sn[2][3*p+2] + sn[3][3*p+2];
      np[p] = make_float4(nx, ny, nz, 0.f);
    }
  } else {
    const int blk = bid - D1_NRM;
    const int gtid = blk * 256 + tid, stride = RED1_BLKS * 256;
    float sp = 0.f, sr = 0.f, sk = 0.f;
    for (int i = gtid; i < B * PARAM_DIM; i += stride) { float d = recon_x[i] - x[i]; sp += d * d; }
    for (int i = gtid; i < B * P1 * 3; i += stride)    { float d = recon_xyz[i] - hand_xyz[i]; sr += d * d; }
    for (int i = gtid; i < B * LATENT; i += stride)    { float lv = logvar[i], m = mu[i]; sk += 1.f + lv - m * m - expf(lv); }
    for (int off = 32; off > 0; off >>= 1) {
      sp += __shfl_down(sp, off, 64);
      sr += __shfl_down(sr, off, 64);
      sk += __shfl_down(sk, off, 64);
    }
    float* sred = (float*)sn;
    const int wv = tid >> 6;
    if ((tid & 63) == 0) { sred[wv*3] = sp; sred[wv*3+1] = sr; sred[wv*3+2] = sk; }
    __syncthreads();
    if (tid == 0) {
      float a = 0.f, bb = 0.f, c = 0.f;
      for (int w = 0; w < 4; ++w) { a += sred[w*3]; bb += sred[w*3+1]; c += sred[w*3+2]; }
      ws[R1_OFF + blk*3+0] = a; ws[R1_OFF + blk*3+1] = bb; ws[R1_OFF + blk*3+2] = c;
    }
  }
}

// ---------------- D2: fused o2h + h2o via MFMA distance tiles ----------------
// Grid: (chunk of 192 obj pts, set, b) = 16*2*32 = 1024 blocks, 4 blocks/CU.
// Waves split the 49 hand tiles (13/12/12/12); every wave sweeps all 12 obj
// tiles of the chunk (B-frags in registers). A-frags built JIT from the LDS
// vert tile. h2o per-tile 16-lane reduce via DPP. Consume uses an SGPR mask
// (readfirstlane) so (d & mask) | idx emits v_and_or_b32, and a balanced
// umin tree for v_min3_u32 pairs.
__global__ __launch_bounds__(256, 4) void kd2(
    const float* __restrict__ recon_xyz, const float* __restrict__ hand_xyz,
    const float* __restrict__ obj, float* __restrict__ ws) {
  __shared__ float4 sVerts[P1PAD];             // 12544 B (xyz, w=|h|^2)
  __shared__ float4 sObj[CHO];                 // 3072 B (xyz, w=|o|^2)
  __shared__ unsigned sKeys[4][CHO];           // 3072 B per-wave o2h keys

  const int tid = threadIdx.x;
  const int bid = blockIdx.x;
  const int chunk = bid >> 6, rr = bid & 63, set = rr >> 5, b = rr & 31;
  const float* verts = (set == 0 ? recon_xyz : hand_xyz) + b * P1 * 3;
  const float* op = obj + (size_t)b * P2 * 3;

  for (int i = tid; i < P1PAD; i += 256) {
    float vx, vy, vz;
    if (i < P1) { vx = verts[3*i]; vy = verts[3*i+1]; vz = verts[3*i+2]; }
    else        { vx = vy = vz = 1.0e6f; }     // far pad row: never argmin
    sVerts[i] = make_float4(vx, vy, vz, vx*vx + vy*vy + vz*vz);
  }
  for (int i = tid; i < CHO; i += 256) {
    const int q = chunk * CHO + i;
    float ox, oy, oz;
    if (q < P2) { ox = op[3*q]; oy = op[3*q+1]; oz = op[3*q+2]; }
    else        { ox = oy = oz = 1.0e6f; }     // pad: huge d2, never wins, discarded
    sObj[i] = make_float4(ox, oy, oz, ox*ox + oy*oy + oz*oz);
  }
  __syncthreads();

  // key mask hoisted to SGPR: enables v_and_or_b32 (VOP3 can't take the literal)
  const unsigned maskS = (unsigned)__builtin_amdgcn_readfirstlane(0xFFFFFC00u);

  // ---- pack B fragments (obj side) into registers, identical per wave ----
  const int l = tid & 63, wv = tid >> 6, g = l >> 4, cl = l & 15;
  U4 bw[NTO];
  #pragma unroll
  for (int j = 0; j < NTO; ++j) {
    const float4 o = sObj[j * 16 + cl];
    unsigned u0 = 0u, u1 = 0u, u2 = 0u, u3 = 0u;
    if (g == 0) {              // k0..7: ohx ohy ohz ohx ohy ohz olx oly
      const unsigned ohx = bhi(o.x), ohy = bhi(o.y), ohz = bhi(o.z);
      const unsigned olx = bhi(bres(o.x, ohx));
      const unsigned oly = bhi(bres(o.y, ohy));
      u0 = ohx | (ohy << 16);
      u1 = ohz | (ohx << 16);
      u2 = ohy | (ohz << 16);
      u3 = olx | (oly << 16);
    } else if (g == 1) {       // k8..15: olz 1 1 o2h o2l 0 0 0
      const unsigned ohz = bhi(o.z);
      const unsigned olz = bhi(bres(o.z, ohz));
      const float o2p = o.w + 1.0f;            // +1 bias keeps d2' > 0 for key-min
      const unsigned o2h = bhi(o2p);
      const unsigned o2l = bhi(bres(o2p, o2h));
      u0 = olz | (0x3F80u << 16);
      u1 = 0x3F80u | (o2h << 16);
      u2 = o2l;
      u3 = 0u;
    }
    bw[j].u = make_uint4(u0, u1, u2, u3);
  }

  // ---- main sweep: this wave's hand tiles (t = wv, wv+4, ...) x 12 obj tiles
  unsigned om[NTO];
  #pragma unroll
  for (int j = 0; j < NTO; ++j) om[j] = 0xFFFFFFFFu;

  float* hpart = ws + HP_OFF + (size_t)(((chunk * 2) + set) * B + b) * P1PAD;
  const f32x4 czero = {0.f, 0.f, 0.f, 0.f};
  const int nt = (NTH - wv + 3) >> 2;          // wave0: 13, waves1-3: 12

  for (int s = 0; s < nt; ++s) {
    const int t = wv + 4 * s;
    const int ib = t * 16 + g * 4;             // this lane's hand-row base
    const unsigned ib0 = (unsigned)ib, ib1 = (unsigned)(ib + 1);
    const unsigned ib2 = (unsigned)(ib + 2), ib3 = (unsigned)(ib + 3);
    // ---- JIT A-frag from sVerts (lanes 0-31; lanes 32-63 carry k16-31 = 0) --
    U4 ac;
    if (l < 32) {
      const float4 v = sVerts[t * 16 + cl];
      if (g == 0) {            // k0..7: hhx hhy hhz hlx hly hlz hhx hhy
        const float sx = -2.f * v.x, sy = -2.f * v.y, sz = -2.f * v.z;
        const unsigned hx = bhi(sx), hy = bhi(sy), hz = bhi(sz);
        const unsigned lx = bhi(bres(sx, hx));
        const unsigned ly = bhi(bres(sy, hy));
        const unsigned lz = bhi(bres(sz, hz));
        ac.u = make_uint4(hx | (hy << 16), hz | (lx << 16),
                          ly | (lz << 16), hx | (hy << 16));
      } else {                 // k8..15: hhz h2h h2l 1 1 0 0 0
        const float sz = -2.f * v.z;
        const unsigned hz = bhi(sz);
        const unsigned h2h = bhi(v.w);
        const unsigned h2l = bhi(bres(v.w, h2h));
        ac.u = make_uint4(hz | (h2h << 16), h2l | (0x3F80u << 16), 0x3F80u, 0u);
      }
    } else {
      ac.u = make_uint4(0u, 0u, 0u, 0u);
    }
    float hm0 = 3.0e38f, hm1 = 3.0e38f, hm2 = 3.0e38f, hm3 = 3.0e38f;
    // ---- two half-sweeps: issue NTOH independent MFMAs, then consume ----
    #pragma unroll
    for (int hs = 0; hs < 2; ++hs) {
      f32x4 dd[NTOH];
      #pragma unroll
      for (int j = 0; j < NTOH; ++j)
        dd[j] = __builtin_amdgcn_mfma_f32_16x16x32_bf16(ac.v, bw[hs * NTOH + j].v, czero, 0, 0, 0);
      #pragma unroll
      for (int j = 0; j < NTOH; ++j) {
        const f32x4 d = dd[j];
        hm0 = fminf(hm0, d[0]); hm1 = fminf(hm1, d[1]);
        hm2 = fminf(hm2, d[2]); hm3 = fminf(hm3, d[3]);
        // (d & maskS) | ibN -> v_and_or_b32 (SGPR mask); balanced tree -> v_min3_u32
        const unsigned k0 = (__float_as_uint(d[0]) & maskS) | ib0;
        const unsigned k1 = (__float_as_uint(d[1]) & maskS) | ib1;
        const unsigned k2 = (__float_as_uint(d[2]) & maskS) | ib2;
        const unsigned k3 = (__float_as_uint(d[3]) & maskS) | ib3;
        om[hs * NTOH + j] = umin2(umin2(umin2(k0, k1), umin2(k2, k3)), om[hs * NTOH + j]);
      }
    }
    // h2o: DPP min-reduce across the 16 cols (contiguous lanes sharing g)
    hm0 = row_min16(hm0);
    hm1 = row_min16(hm1);
    hm2 = row_min16(hm2);
    hm3 = row_min16(hm3);
    if (cl == 0)
      *(float4*)&hpart[ib] = make_float4(hm0 - 1.f, hm1 - 1.f, hm2 - 1.f, hm3 - 1.f);
  }

  // ---- o2h: fold the 4 row-groups within the wave, publish per-wave keys ----
  #pragma unroll
  for (int j = 0; j < NTO; ++j) {
    unsigned v = umin2(om[j], (unsigned)__shfl_xor((int)om[j], 16, 64));
    v = umin2(v, (unsigned)__shfl_xor((int)v, 32, 64));
    if (l < 16) sKeys[wv][j * 16 + l] = v;
  }
  __syncthreads();

  // ---- o2h epilogue: fold 4 waves, exact recompute + sign from raw normals --
  const float4* npb = (const float4*)(ws + NP_OFF);
  float* os = ws + OS_OFF + (size_t)(set * B + b) * P2;
  for (int i = tid; i < CHO; i += 256) {
    const int q = chunk * CHO + i;
    if (q < P2) {
      const unsigned key = umin2(umin2(sKeys[0][i], sKeys[1][i]),
                                 umin2(sKeys[2][i], sKeys[3][i]));
      int hi = (int)(key & 1023u); if (hi > P1 - 1) hi = P1 - 1;
      const float4 h = sVerts[hi];
      const float4 o = sObj[i];
      const float dx = o.x - h.x, dy = o.y - h.y, dz = o.z - h.z;
      const float d2 = fmaf(dx, dx, fmaf(dy, dy, dz * dz));
      const float4 n0 = npb[(size_t)((0 * 2 + set) * B + b) * P1 + hi];
      const float4 n1 = npb[(size_t)((1 * 2 + set) * B + b) * P1 + hi];
      const float4 n2 = npb[(size_t)((2 * 2 + set) * B + b) * P1 + hi];
      const float4 n3 = npb[(size_t)((3 * 2 + set) * B + b) * P1 + hi];
      const float nx = (n0.x + n1.x) + (n2.x + n3.x);
      const float ny = (n0.y + n1.y) + (n2.y + n3.y);
      const float nz = (n0.z + n1.z) + (n2.z + n3.z);
      const float dt = nx * dx + ny * dy + nz * dz;
      const float sg = (dt > 0.f) ? 1.f : ((dt < 0.f) ? -1.f : 0.f);
      os[q] = sqrtf(d2) * sg;
    }
  }
}

// ---------------- D3: o-combine ∥ h-combine ----------------------------------
__global__ __launch_bounds__(256) void kd3(const float* __restrict__ vw,
                                           float* __restrict__ ws) {
  __shared__ float sred[4];
  const int tid = threadIdx.x;
  const int bid = blockIdx.x;
  if (bid < OC_BLKS) {
    const int gtid = bid * 256 + tid, stride = OC_BLKS * 256;
    float so = 0.f;
    for (int i = gtid; i < B * P2; i += stride) {
      float osA = ws[OS_OFF + i];
      float osB = ws[OS_OFF + (size_t)B * P2 + i];
      bool wdist = (osB < 0.01f) && (osB > -0.005f);
      float w = (osA < 0.f) ? 1.5f : (wdist ? 1.f : 0.1f);
      so += fabsf(osA - osB) * w;
    }
    for (int off = 32; off > 0; off >>= 1) so += __shfl_down(so, off, 64);
    if ((tid & 63) == 0) sred[tid >> 6] = so;
    __syncthreads();
    if (tid == 0) ws[RO_OFF + bid] = sred[0] + sred[1] + sred[2] + sred[3];
  } else {
    const int blk = bid - OC_BLKS;
    const int gtid = blk * 256 + tid, stride = HC_BLKS * 256;
    float sh = 0.f;
    for (int i = gtid; i < B * P1; i += stride) {
      const int p = i % P1, bb = i / P1;
      const size_t base0 = (size_t)HP_OFF + (size_t)bb * P1PAD + p;
      float m0 = 3.0e38f, m1 = 3.0e38f;
      #pragma unroll
      for (int c = 0; c < NPART; ++c) {
        m0 = fminf(m0, ws[base0 + (size_t)(c*2+0) * B * P1PAD]);
        m1 = fminf(m1, ws[base0 + (size_t)(c*2+1) * B * P1PAD]);
      }
      m0 = fmaxf(m0, 0.f); m1 = fmaxf(m1, 0.f);
      sh += fabsf(sqrtf(m0) - sqrtf(m1)) * powf(vw[p], 0.4f);
    }
    for (int off = 32; off > 0; off >>= 1) sh += __shfl_down(sh, off, 64);
    if ((tid & 63) == 0) sred[tid >> 6] = sh;
    __syncthreads();
    if (tid == 0) ws[RH_OFF + blk] = sred[0] + sred[1] + sred[2] + sred[3];
  }
}

// ---------------- D4: finalize (single wave) ---------------------------------
__global__ void kfin(const float* __restrict__ ws, float* __restrict__ out) {
  const int lane = threadIdx.x;
  float sp = 0.f, sr = 0.f, sk = 0.f, sh = 0.f, so = 0.f;
  for (int i = lane; i < RED1_BLKS; i += 64) {
    sp += ws[R1_OFF + i*3+0]; sr += ws[R1_OFF + i*3+1]; sk += ws[R1_OFF + i*3+2];
  }
  for (int i = lane; i < HC_BLKS; i += 64) sh += ws[RH_OFF + i];
  for (int i = lane; i < OC_BLKS; i += 64) so += ws[RO_OFF + i];
  for (int off = 32; off > 0; off >>= 1) {
    sp += __shfl_down(sp, off, 64);
    sr += __shfl_down(sr, off, 64);
    sk += __shfl_down(sk, off, 64);
    sh += __shfl_down(sh, off, 64);
    so += __shfl_down(so, off, 64);
  }
  if (lane == 0) {
    float param_loss = sp / (float)B;
    float recon_loss = sr / (float)B;
    float KLD = -0.5f * sk / (float)B;
    float cvae = recon_loss + KLD;
    float loss_h = 35.f * (1.f - 0.005f) * sh / (float)(B * P1);
    float loss_o = 30.f * (1.f - 0.005f) * so / (float)(B * P2);
    float ho = loss_h + loss_o;
    out[0] = cvae + 0.1f * param_loss + 10.f * ho;
    out[1] = param_loss;
    out[2] = ho;
    out[3] = recon_loss;
    out[4] = KLD;
  }
}

extern "C" void kernel_launch(void* const* d_in, const int* in_sizes, int n_in,
                              void* d_out, int out_size, void* d_ws, size_t ws_size,
                              hipStream_t stream) {
  const float* recon_x   = (const float*)d_in[0];
  const float* x         = (const float*)d_in[1];
  const float* mu        = (const float*)d_in[2];
  const float* logvar    = (const float*)d_in[3];
  const float* recon_xyz = (const float*)d_in[4];
  const float* hand_xyz  = (const float*)d_in[5];
  const int*   faces     = (const int*)d_in[6];
  const float* obj       = (const float*)d_in[7];
  const float* vw        = (const float*)d_in[8];
  float* ws = (float*)d_ws;
  float* out = (float*)d_out;

  kd1<<<dim3(D1_TOT), 256, 0, stream>>>(recon_x, x, mu, logvar,
                                        recon_xyz, hand_xyz, faces, ws);
  kd2<<<dim3(D2_TOT), 256, 0, stream>>>(recon_xyz, hand_xyz, obj, ws);
  kd3<<<dim3(D3_TOT), 256, 0, stream>>>(vw, ws);
  kfin<<<1, 64, 0, stream>>>(ws, out);
}

// Round 12
// 111.780 us; speedup vs baseline: 1.3139x; 1.0466x over previous
//
#include <hip/hip_runtime.h>
#include <math.h>

#define B 32
#define P1 778
#define NF 1538
#define P2 3000
#define PARAM_DIM 61
#define LATENT 64

// ---- MFMA kd2 geometry ----
#define P1PAD 784            // 49 hand tiles of 16
#define NTH 49               // hand tiles
#define CHO 192              // obj pts per block (16 chunks cover 3000..3072)
#define NTO 12               // obj tiles (of 16) per block; all waves sweep all 12
#define NTOH 6               // MFMA cluster depth (dd[] register budget)
#define NCH 16               // obj chunks -> grid 1024 = 4 blocks/CU

#define RED1_BLKS 16
#define HC_BLKS 128
#define OC_BLKS 192
#define QF 385               // faces per quarter-split (3*385 + 383 = 1538)

#define D1_NRM 256           // 4 quarters * 2 sets * 32 batches
#define D1_TOT (D1_NRM + RED1_BLKS)
#define D2_TOT (NCH * 64)    // 1024 blocks
#define D3_TOT (OC_BLKS + HC_BLKS)

// ws layout (float offsets)
#define NP_OFF  0
#define NP_SZ   (4*2*B*P1*4)           // [quarter*2+set][b][p] float4 raw normals
#define OS_OFF  (NP_OFF + NP_SZ)       // signed o2h distances (float)
#define OS_SZ   (2*B*P2)
#define HP_OFF  (OS_OFF + OS_SZ)       // h2o mins: ONE plane per (set,b), uint-as-float
#define HP_SZ   (2*B*P1PAD)
#define R1_OFF  (HP_OFF + HP_SZ)
#define RH_OFF  (R1_OFF + RED1_BLKS*3)
#define RO_OFF  (RH_OFF + HC_BLKS)

typedef __attribute__((ext_vector_type(8))) short bf16x8;
typedef __attribute__((ext_vector_type(4))) float f32x4;
union U4 { uint4 u; bf16x8 v; };

static __device__ __forceinline__ unsigned umin2(unsigned a, unsigned b) { return a < b ? a : b; }
// top 16 bits of an f32 = bf16 by truncation (residual stays exactly representable)
static __device__ __forceinline__ unsigned bhi(float x) { return __float_as_uint(x) >> 16; }
static __device__ __forceinline__ float bres(float x, unsigned h) { return x - __uint_as_float(h << 16); }

// DPP min-reduce stage across a 16-lane row (no DS pipe, no waitcnt).
// CTRL: 0xB1 = quad_perm[1,0,3,2], 0x4E = quad_perm[2,3,0,1],
//       0x124 = row_ror:4, 0x128 = row_ror:8. Rotation valid for commutative min.
template <int CTRL>
static __device__ __forceinline__ float dpp_min(float x) {
  const int xi = __float_as_int(x);
  const int yi = __builtin_amdgcn_update_dpp(xi, xi, CTRL, 0xF, 0xF, false);
  return fminf(x, __int_as_float(yi));
}
static __device__ __forceinline__ float row_min16(float x) {
  x = dpp_min<0xB1>(x);
  x = dpp_min<0x4E>(x);
  x = dpp_min<0x124>(x);
  x = dpp_min<0x128>(x);
  return x;
}

// ---------------- D1: raw vertex-normal partials (4 blocks/mesh) + red1 ------
__global__ __launch_bounds__(256) void kd1(
    const float* __restrict__ recon_x, const float* __restrict__ x,
    const float* __restrict__ mu, const float* __restrict__ logvar,
    const float* __restrict__ recon_xyz, const float* __restrict__ hand_xyz,
    const int* __restrict__ faces, float* __restrict__ ws) {
  __shared__ float4 sv[P1];           // 12448 B
  __shared__ float sn[4][2336];       // wave-private accumulators, 37376 B
  const int tid = threadIdx.x;
  const int bid = blockIdx.x;

  if (bid < D1_NRM) {
    const int q = bid >> 6, r = bid & 63, set = r >> 5, b = r & 31;
    const float* verts = (set == 0 ? recon_xyz : hand_xyz) + b * P1 * 3;
    const int* f = faces + b * NF * 3 + q * QF * 3;
    const int nf = (q < 3) ? QF : (NF - 3 * QF);
    for (int i = tid; i < P1; i += 256)
      sv[i] = make_float4(verts[3*i], verts[3*i+1], verts[3*i+2], 0.f);
    for (int i = tid; i < 4 * 2336; i += 256) ((float*)sn)[i] = 0.f;
    __syncthreads();
    float* s = sn[tid >> 6];          // wave-private: no cross-wave contention
    for (int k = tid; k < nf; k += 256) {
      int i0 = f[3*k], i1 = f[3*k+1], i2 = f[3*k+2];
      float4 v0 = sv[i0], v1 = sv[i1], v2 = sv[i2];
      float e0x = v1.x - v0.x, e0y = v1.y - v0.y, e0z = v1.z - v0.z;
      float e1x = v2.x - v0.x, e1y = v2.y - v0.y, e1z = v2.z - v0.z;
      float fx = e0y * e1z - e0z * e1y;
      float fy = e0z * e1x - e0x * e1z;
      float fz = e0x * e1y - e0y * e1x;
      atomicAdd(&s[3*i0+0], fx); atomicAdd(&s[3*i0+1], fy); atomicAdd(&s[3*i0+2], fz);
      atomicAdd(&s[3*i1+0], fx); atomicAdd(&s[3*i1+1], fy); atomicAdd(&s[3*i1+2], fz);
      atomicAdd(&s[3*i2+0], fx); atomicAdd(&s[3*i2+1], fy); atomicAdd(&s[3*i2+2], fz);
    }
    __syncthreads();
    // sign(n.v) is invariant under positive scaling -> store RAW sums, no normalize
    float4* np = (float4*)(ws + NP_OFF) + (size_t)((q * 2 + set) * B + b) * P1;
    for (int p = tid; p < P1; p += 256) {
      float nx = sn[0][3*p] + sn[1][3*p] + sn[2][3*p] + sn[3][3*p];
      float ny = sn[0][3*p+1] + sn[1][3*p+1] + sn[2][3*p+1] + sn[3][3*p+1];
      float nz = sn[0][3*p+2] + sn[1][3*p+2] + sn[2][3*p+2] + sn[3][3*p+2];
      np[p] = make_float4(nx, ny, nz, 0.f);
    }
  } else {
    const int blk = bid - D1_NRM;
    const int gtid = blk * 256 + tid, stride = RED1_BLKS * 256;
    // init HP planes to uint-max so kd2's atomicMin always wins (poison-safe)
    {
      unsigned* hp = (unsigned*)(ws + HP_OFF);
      for (int i = gtid; i < 2 * B * P1PAD; i += stride) hp[i] = 0xFFFFFFFFu;
    }
    float sp = 0.f, sr = 0.f, sk = 0.f;
    for (int i = gtid; i < B * PARAM_DIM; i += stride) { float d = recon_x[i] - x[i]; sp += d * d; }
    for (int i = gtid; i < B * P1 * 3; i += stride)    { float d = recon_xyz[i] - hand_xyz[i]; sr += d * d; }
    for (int i = gtid; i < B * LATENT; i += stride)    { float lv = logvar[i], m = mu[i]; sk += 1.f + lv - m * m - expf(lv); }
    for (int off = 32; off > 0; off >>= 1) {
      sp += __shfl_down(sp, off, 64);
      sr += __shfl_down(sr, off, 64);
      sk += __shfl_down(sk, off, 64);
    }
    float* sred = (float*)sn;
    const int wv = tid >> 6;
    if ((tid & 63) == 0) { sred[wv*3] = sp; sred[wv*3+1] = sr; sred[wv*3+2] = sk; }
    __syncthreads();
    if (tid == 0) {
      float a = 0.f, bb = 0.f, c = 0.f;
      for (int w = 0; w < 4; ++w) { a += sred[w*3]; bb += sred[w*3+1]; c += sred[w*3+2]; }
      ws[R1_OFF + blk*3+0] = a; ws[R1_OFF + blk*3+1] = bb; ws[R1_OFF + blk*3+2] = c;
    }
  }
}

// ---------------- D2: fused o2h + h2o via MFMA distance tiles ----------------
// Grid: (chunk of 192 obj pts, set, b) = 16*2*32 = 1024 blocks, 4 blocks/CU.
// Waves split the 49 hand tiles (13/12/12/12); every wave sweeps all 12 obj
// tiles of the chunk (B-frags in registers). A-frags built JIT from the LDS
// vert tile. h2o per-tile 16-lane reduce via DPP, then device atomicMin on a
// SINGLE uint plane per (set,b): positive-float uint order == float order,
// and the +1-biased hm is always > 0.
__global__ __launch_bounds__(256, 4) void kd2(
    const float* __restrict__ recon_xyz, const float* __restrict__ hand_xyz,
    const float* __restrict__ obj, float* __restrict__ ws) {
  __shared__ float4 sVerts[P1PAD];             // 12544 B (xyz, w=|h|^2)
  __shared__ float4 sObj[CHO];                 // 3072 B (xyz, w=|o|^2)
  __shared__ unsigned sKeys[4][CHO];           // 3072 B per-wave o2h keys

  const int tid = threadIdx.x;
  const int bid = blockIdx.x;
  const int chunk = bid >> 6, rr = bid & 63, set = rr >> 5, b = rr & 31;
  const float* verts = (set == 0 ? recon_xyz : hand_xyz) + b * P1 * 3;
  const float* op = obj + (size_t)b * P2 * 3;

  for (int i = tid; i < P1PAD; i += 256) {
    float vx, vy, vz;
    if (i < P1) { vx = verts[3*i]; vy = verts[3*i+1]; vz = verts[3*i+2]; }
    else        { vx = vy = vz = 1.0e6f; }     // far pad row: never argmin
    sVerts[i] = make_float4(vx, vy, vz, vx*vx + vy*vy + vz*vz);
  }
  for (int i = tid; i < CHO; i += 256) {
    const int q = chunk * CHO + i;
    float ox, oy, oz;
    if (q < P2) { ox = op[3*q]; oy = op[3*q+1]; oz = op[3*q+2]; }
    else        { ox = oy = oz = 1.0e6f; }     // pad: huge d2, never wins, discarded
    sObj[i] = make_float4(ox, oy, oz, ox*ox + oy*oy + oz*oz);
  }
  __syncthreads();

  // key mask hoisted to SGPR: enables v_and_or_b32 (VOP3 can't take the literal)
  const unsigned maskS = (unsigned)__builtin_amdgcn_readfirstlane(0xFFFFFC00u);

  // ---- pack B fragments (obj side) into registers, identical per wave ----
  const int l = tid & 63, wv = tid >> 6, g = l >> 4, cl = l & 15;
  U4 bw[NTO];
  #pragma unroll
  for (int j = 0; j < NTO; ++j) {
    const float4 o = sObj[j * 16 + cl];
    unsigned u0 = 0u, u1 = 0u, u2 = 0u, u3 = 0u;
    if (g == 0) {              // k0..7: ohx ohy ohz ohx ohy ohz olx oly
      const unsigned ohx = bhi(o.x), ohy = bhi(o.y), ohz = bhi(o.z);
      const unsigned olx = bhi(bres(o.x, ohx));
      const unsigned oly = bhi(bres(o.y, ohy));
      u0 = ohx | (ohy << 16);
      u1 = ohz | (ohx << 16);
      u2 = ohy | (ohz << 16);
      u3 = olx | (oly << 16);
    } else if (g == 1) {       // k8..15: olz 1 1 o2h o2l 0 0 0
      const unsigned ohz = bhi(o.z);
      const unsigned olz = bhi(bres(o.z, ohz));
      const float o2p = o.w + 1.0f;            // +1 bias keeps d2' > 0 for key-min
      const unsigned o2h = bhi(o2p);
      const unsigned o2l = bhi(bres(o2p, o2h));
      u0 = olz | (0x3F80u << 16);
      u1 = 0x3F80u | (o2h << 16);
      u2 = o2l;
      u3 = 0u;
    }
    bw[j].u = make_uint4(u0, u1, u2, u3);
  }

  // ---- main sweep: this wave's hand tiles (t = wv, wv+4, ...) x 12 obj tiles
  unsigned om[NTO];
  #pragma unroll
  for (int j = 0; j < NTO; ++j) om[j] = 0xFFFFFFFFu;

  unsigned* hp = (unsigned*)(ws + HP_OFF) + (size_t)(set * B + b) * P1PAD;
  const f32x4 czero = {0.f, 0.f, 0.f, 0.f};
  const int nt = (NTH - wv + 3) >> 2;          // wave0: 13, waves1-3: 12

  for (int s = 0; s < nt; ++s) {
    const int t = wv + 4 * s;
    const int ib = t * 16 + g * 4;             // this lane's hand-row base
    const unsigned ib0 = (unsigned)ib, ib1 = (unsigned)(ib + 1);
    const unsigned ib2 = (unsigned)(ib + 2), ib3 = (unsigned)(ib + 3);
    // ---- JIT A-frag from sVerts (lanes 0-31; lanes 32-63 carry k16-31 = 0) --
    U4 ac;
    if (l < 32) {
      const float4 v = sVerts[t * 16 + cl];
      if (g == 0) {            // k0..7: hhx hhy hhz hlx hly hlz hhx hhy
        const float sx = -2.f * v.x, sy = -2.f * v.y, sz = -2.f * v.z;
        const unsigned hx = bhi(sx), hy = bhi(sy), hz = bhi(sz);
        const unsigned lx = bhi(bres(sx, hx));
        const unsigned ly = bhi(bres(sy, hy));
        const unsigned lz = bhi(bres(sz, hz));
        ac.u = make_uint4(hx | (hy << 16), hz | (lx << 16),
                          ly | (lz << 16), hx | (hy << 16));
      } else {                 // k8..15: hhz h2h h2l 1 1 0 0 0
        const float sz = -2.f * v.z;
        const unsigned hz = bhi(sz);
        const unsigned h2h = bhi(v.w);
        const unsigned h2l = bhi(bres(v.w, h2h));
        ac.u = make_uint4(hz | (h2h << 16), h2l | (0x3F80u << 16), 0x3F80u, 0u);
      }
    } else {
      ac.u = make_uint4(0u, 0u, 0u, 0u);
    }
    float hm0 = 3.0e38f, hm1 = 3.0e38f, hm2 = 3.0e38f, hm3 = 3.0e38f;
    // ---- two half-sweeps: issue NTOH independent MFMAs, then consume ----
    #pragma unroll
    for (int hs = 0; hs < 2; ++hs) {
      f32x4 dd[NTOH];
      #pragma unroll
      for (int j = 0; j < NTOH; ++j)
        dd[j] = __builtin_amdgcn_mfma_f32_16x16x32_bf16(ac.v, bw[hs * NTOH + j].v, czero, 0, 0, 0);
      #pragma unroll
      for (int j = 0; j < NTOH; ++j) {
        const f32x4 d = dd[j];
        hm0 = fminf(hm0, d[0]); hm1 = fminf(hm1, d[1]);
        hm2 = fminf(hm2, d[2]); hm3 = fminf(hm3, d[3]);
        // (d & maskS) | ibN -> v_and_or_b32 (SGPR mask); balanced tree -> v_min3_u32
        const unsigned k0 = (__float_as_uint(d[0]) & maskS) | ib0;
        const unsigned k1 = (__float_as_uint(d[1]) & maskS) | ib1;
        const unsigned k2 = (__float_as_uint(d[2]) & maskS) | ib2;
        const unsigned k3 = (__float_as_uint(d[3]) & maskS) | ib3;
        om[hs * NTOH + j] = umin2(umin2(umin2(k0, k1), umin2(k2, k3)), om[hs * NTOH + j]);
      }
    }
    // h2o: DPP min-reduce across the 16 cols (contiguous lanes sharing g),
    // then one device atomicMin per hand row (uint order == float order, hm>0)
    hm0 = row_min16(hm0);
    hm1 = row_min16(hm1);
    hm2 = row_min16(hm2);
    hm3 = row_min16(hm3);
    if (cl == 0) {
      atomicMin(&hp[ib + 0], __float_as_uint(hm0));
      atomicMin(&hp[ib + 1], __float_as_uint(hm1));
      atomicMin(&hp[ib + 2], __float_as_uint(hm2));
      atomicMin(&hp[ib + 3], __float_as_uint(hm3));
    }
  }

  // ---- o2h: fold the 4 row-groups within the wave, publish per-wave keys ----
  #pragma unroll
  for (int j = 0; j < NTO; ++j) {
    unsigned v = umin2(om[j], (unsigned)__shfl_xor((int)om[j], 16, 64));
    v = umin2(v, (unsigned)__shfl_xor((int)v, 32, 64));
    if (l < 16) sKeys[wv][j * 16 + l] = v;
  }
  __syncthreads();

  // ---- o2h epilogue: fold 4 waves, exact recompute + sign from raw normals --
  const float4* npb = (const float4*)(ws + NP_OFF);
  float* os = ws + OS_OFF + (size_t)(set * B + b) * P2;
  for (int i = tid; i < CHO; i += 256) {
    const int q = chunk * CHO + i;
    if (q < P2) {
      const unsigned key = umin2(umin2(sKeys[0][i], sKeys[1][i]),
                                 umin2(sKeys[2][i], sKeys[3][i]));
      int hi = (int)(key & 1023u); if (hi > P1 - 1) hi = P1 - 1;
      const float4 h = sVerts[hi];
      const float4 o = sObj[i];
      const float dx = o.x - h.x, dy = o.y - h.y, dz = o.z - h.z;
      const float d2 = fmaf(dx, dx, fmaf(dy, dy, dz * dz));
      const float4 n0 = npb[(size_t)((0 * 2 + set) * B + b) * P1 + hi];
      const float4 n1 = npb[(size_t)((1 * 2 + set) * B + b) * P1 + hi];
      const float4 n2 = npb[(size_t)((2 * 2 + set) * B + b) * P1 + hi];
      const float4 n3 = npb[(size_t)((3 * 2 + set) * B + b) * P1 + hi];
      const float nx = (n0.x + n1.x) + (n2.x + n3.x);
      const float ny = (n0.y + n1.y) + (n2.y + n3.y);
      const float nz = (n0.z + n1.z) + (n2.z + n3.z);
      const float dt = nx * dx + ny * dy + nz * dz;
      const float sg = (dt > 0.f) ? 1.f : ((dt < 0.f) ? -1.f : 0.f);
      os[q] = sqrtf(d2) * sg;
    }
  }
}

// ---------------- D3: o-combine ∥ h-combine ----------------------------------
__global__ __launch_bounds__(256) void kd3(const float* __restrict__ vw,
                                           float* __restrict__ ws) {
  __shared__ float sred[4];
  const int tid = threadIdx.x;
  const int bid = blockIdx.x;
  if (bid < OC_BLKS) {
    const int gtid = bid * 256 + tid, stride = OC_BLKS * 256;
    float so = 0.f;
    for (int i = gtid; i < B * P2; i += stride) {
      float osA = ws[OS_OFF + i];
      float osB = ws[OS_OFF + (size_t)B * P2 + i];
      bool wdist = (osB < 0.01f) && (osB > -0.005f);
      float w = (osA < 0.f) ? 1.5f : (wdist ? 1.f : 0.1f);
      so += fabsf(osA - osB) * w;
    }
    for (int off = 32; off > 0; off >>= 1) so += __shfl_down(so, off, 64);
    if ((tid & 63) == 0) sred[tid >> 6] = so;
    __syncthreads();
    if (tid == 0) ws[RO_OFF + bid] = sred[0] + sred[1] + sred[2] + sred[3];
  } else {
    const int blk = bid - OC_BLKS;
    const int gtid = blk * 256 + tid, stride = HC_BLKS * 256;
    const unsigned* hpb = (const unsigned*)(ws + HP_OFF);
    float sh = 0.f;
    for (int i = gtid; i < B * P1; i += stride) {
      const int p = i % P1, bb = i / P1;
      float m0 = __uint_as_float(hpb[(size_t)bb * P1PAD + p]) - 1.f;
      float m1 = __uint_as_float(hpb[(size_t)(B + bb) * P1PAD + p]) - 1.f;
      m0 = fmaxf(m0, 0.f); m1 = fmaxf(m1, 0.f);
      sh += fabsf(sqrtf(m0) - sqrtf(m1)) * powf(vw[p], 0.4f);
    }
    for (int off = 32; off > 0; off >>= 1) sh += __shfl_down(sh, off, 64);
    if ((tid & 63) == 0) sred[tid >> 6] = sh;
    __syncthreads();
    if (tid == 0) ws[RH_OFF + blk] = sred[0] + sred[1] + sred[2] + sred[3];
  }
}

// ---------------- D4: finalize (single wave) ---------------------------------
__global__ void kfin(const float* __restrict__ ws, float* __restrict__ out) {
  const int lane = threadIdx.x;
  float sp = 0.f, sr = 0.f, sk = 0.f, sh = 0.f, so = 0.f;
  for (int i = lane; i < RED1_BLKS; i += 64) {
    sp += ws[R1_OFF + i*3+0]; sr += ws[R1_OFF + i*3+1]; sk += ws[R1_OFF + i*3+2];
  }
  for (int i = lane; i < HC_BLKS; i += 64) sh += ws[RH_OFF + i];
  for (int i = lane; i < OC_BLKS; i += 64) so += ws[RO_OFF + i];
  for (int off = 32; off > 0; off >>= 1) {
    sp += __shfl_down(sp, off, 64);
    sr += __shfl_down(sr, off, 64);
    sk += __shfl_down(sk, off, 64);
    sh += __shfl_down(sh, off, 64);
    so += __shfl_down(so, off, 64);
  }
  if (lane == 0) {
    float param_loss = sp / (float)B;
    float recon_loss = sr / (float)B;
    float KLD = -0.5f * sk / (float)B;
    float cvae = recon_loss + KLD;
    float loss_h = 35.f * (1.f - 0.005f) * sh / (float)(B * P1);
    float loss_o = 30.f * (1.f - 0.005f) * so / (float)(B * P2);
    float ho = loss_h + loss_o;
    out[0] = cvae + 0.1f * param_loss + 10.f * ho;
    out[1] = param_loss;
    out[2] = ho;
    out[3] = recon_loss;
    out[4] = KLD;
  }
}

extern "C" void kernel_launch(void* const* d_in, const int* in_sizes, int n_in,
                              void* d_out, int out_size, void* d_ws, size_t ws_size,
                              hipStream_t stream) {
  const float* recon_x   = (const float*)d_in[0];
  const float* x         = (const float*)d_in[1];
  const float* mu        = (const float*)d_in[2];
  const float* logvar    = (const float*)d_in[3];
  const float* recon_xyz = (const float*)d_in[4];
  const float* hand_xyz  = (const float*)d_in[5];
  const int*   faces     = (const int*)d_in[6];
  const float* obj       = (const float*)d_in[7];
  const float* vw        = (const float*)d_in[8];
  float* ws = (float*)d_ws;
  float* out = (float*)d_out;

  kd1<<<dim3(D1_TOT), 256, 0, stream>>>(recon_x, x, mu, logvar,
                                        recon_xyz, hand_xyz, faces, ws);
  kd2<<<dim3(D2_TOT), 256, 0, stream>>>(recon_xyz, hand_xyz, obj, ws);
  kd3<<<dim3(D3_TOT), 256, 0, stream>>>(vw, ws);
  kfin<<<1, 64, 0, stream>>>(ws, out);
}